// Round 5
// baseline (422.815 us; speedup 1.0000x reference)
//
#include <hip/hip_runtime.h>
#include <hip/hip_fp16.h>
#include <cmath>

#define D 64
#define KTOT 1024
#define MARGIN_I 32u       // fixed-point margin: 32/16384 = 1.95e-3 (>20 sigma of residual accum err)
#define WLCAP 32768        // refine worklist capacity (expect ~1-2K)
#define PMASK 0x3FFFFu     // low 18 bits: point id (N = 2^18)
#define NB 128             // blocks for hist/place counting sort

typedef __attribute__((ext_vector_type(8))) _Float16 half8;  // 8 fp16 = 4 VGPRs (MFMA A/B frag)
typedef __attribute__((ext_vector_type(4))) float f32x4;     // MFMA C/D frag

static __device__ __forceinline__ unsigned umax(unsigned a, unsigned b) { return a > b ? a : b; }
static __device__ __forceinline__ unsigned umin(unsigned a, unsigned b) { return a < b ? a : b; }

// async global->LDS, 16B per lane. LDS dest must be wave-uniform base + lane*16.
__device__ __forceinline__ void gload_lds16(const unsigned short* g, unsigned short* l)
{
    __builtin_amdgcn_global_load_lds(
        (const __attribute__((address_space(1))) unsigned int*)g,
        (__attribute__((address_space(3))) unsigned int*)l, 16, 0, 0);
}

// ---------------- K0: pack w (x128 prescale, hi+lo fp16) + transpose + wn/wn64 + zero cs ----------------
// blocks [0,nprep): pack; [nprep,nprep+4): wn; [nprep+4,nprep+4+64): zero cs + wl_count
__global__ void k_prep(const float* __restrict__ w, unsigned short* __restrict__ wpack_hi,
                       unsigned short* __restrict__ wpack_lo, float* __restrict__ wT,
                       float* __restrict__ wn, double* __restrict__ wn64,
                       float* __restrict__ cs, int* __restrict__ wl_count, int K)
{
    const int nprep = (D * K) / 256;
    const int bid = blockIdx.x;
    if (bid < nprep) {
        int i = bid * 256 + threadIdx.x;         // i = d*K + k
        int d = i / K, k = i % K;
        float f = w[i];
        _Float16 h = (_Float16)f;                // RNE
        float r = f - (float)h;                  // exact (Sterbenz)
        // prescale by 128 (exact exponent shift): products come out x16384
        _Float16 hs = (_Float16)((float)h * 128.0f);
        _Float16 ls = (_Float16)(r * 128.0f);
        int t = k >> 4, n = k & 15;
        int kc = d >> 5, q = (d >> 3) & 3, j = d & 7;
        size_t fi = ((size_t)((t * 2 + kc) * 64 + q * 16 + n)) * 8 + j;
        wpack_hi[fi] = __half_as_ushort(*(__half*)&hs);
        wpack_lo[fi] = __half_as_ushort(*(__half*)&ls);
        wT[(size_t)k * D + d] = f;
    } else if (bid < nprep + 4) {
        int k = (bid - nprep) * 256 + threadIdx.x;
        if (k >= K) return;
        double s = 0.0;
        for (int d = 0; d < D; ++d) {
            double v = (double)w[(size_t)d * K + k];
            s += v * v;
        }
        wn[k] = 16384.0f * (128.0f - (float)(0.5 * s));  // prescaled biased base
        wn64[k] = 0.5 * s;
    } else {
        int z = bid - nprep - 4;                 // 64 zero-blocks x 1024 floats
        #pragma unroll
        for (int j = 0; j < 4; ++j)
            cs[(size_t)z * 1024 + j * 256 + threadIdx.x] = 0.0f;
        if (z == 0 && threadIdx.x == 0) wl_count[0] = 0;
    }
}

// ---------------- K2: MFMA assign (2-term x, 2-term w; 6 MFMA/tile), batched fixed-point top-2 ----------------
// chunks of 32 codes; dbuf global_load_lds staging; LDS ~21 KB -> 7 blocks/CU (~87% occupancy).
// Occupancy is the lever here: barrier vmcnt-drain stalls are filled by other resident blocks.
__global__ __launch_bounds__(256, 7) void k_assign(
    const float* __restrict__ x, const unsigned short* __restrict__ wpack_hi,
    const unsigned short* __restrict__ wpack_lo, const float* __restrict__ wn,
    unsigned int* __restrict__ idx_out, int* __restrict__ wl, int* __restrict__ wl_count,
    int N, int K)
{
    __shared__ __align__(16) unsigned short lds_hi[2][2048];  // 2 x 4 KB (32 codes x 64 d)
    __shared__ __align__(16) unsigned short lds_lo[2][2048];  // 2 x 4 KB
    __shared__ float lds_wn[KTOT];                            // 4 KB, staged once (prescaled base)
    __shared__ int l_wl[128];
    __shared__ int l_cnt, l_base;

    const int tid = threadIdx.x;
    const int wv = tid >> 6, lane = tid & 63;
    const int col = lane & 15, quad = lane >> 4;
    const long long n0 = (long long)blockIdx.x * 128 + wv * 32;
    if (tid == 0) l_cnt = 0;

    // stage all wn (prescaled) once
    #pragma unroll
    for (int i = 0; i < KTOT / 256; ++i)
        lds_wn[tid + 256 * i] = wn[tid + 256 * i];

    // async-stage chunk 0 into buf 0 (hi + lo, 4 KB each = 1 gload each)
    {
        int off = tid * 8;
        gload_lds16(wpack_hi + off, &lds_hi[0][off]);
        gload_lds16(wpack_lo + off, &lds_lo[0][off]);
    }

    // A-frags: x split hi+lo, both prescaled by 128 (exact shifts)
    half8 a_hi[2][2], a_lo[2][2];
    #pragma unroll
    for (int mt = 0; mt < 2; ++mt) {
        long long row = n0 + mt * 16 + col;
        if (row >= N) row = N - 1;
        const float* xr = x + row * D;
        #pragma unroll
        for (int kc = 0; kc < 2; ++kc) {
            const int dbase = kc * 32 + quad * 8;
            float4 f0 = *(const float4*)(xr + dbase);
            float4 f1 = *(const float4*)(xr + dbase + 4);
            float xs[8] = {f0.x, f0.y, f0.z, f0.w, f1.x, f1.y, f1.z, f1.w};
            half8 h, l;
            #pragma unroll
            for (int j = 0; j < 8; ++j) {
                _Float16 hj = (_Float16)xs[j];
                h[j] = (_Float16)((float)hj * 128.0f);
                l[j] = (_Float16)((xs[j] - (float)hj) * 128.0f);
            }
            a_hi[mt][kc] = h;
            a_lo[mt][kc] = l;
        }
    }

    // packed (fixed-point value<<10 | 1023-code): max_u32 argmax, min/max top-2
    unsigned best[8], sec[8];
    #pragma unroll
    for (int s = 0; s < 8; ++s) { best[s] = 0u; sec[s] = 0u; }

    __syncthreads();   // chunk 0 + wn landed (barrier drains vmcnt)

    const int nchunks = K / 32;   // 32
    for (int c = 0; c < nchunks; ++c) {
        if (c + 1 < nchunks) {   // issue next chunk's async loads; drained at end barrier
            const size_t gb = (size_t)(c + 1) * 2048;
            int off = tid * 8;
            gload_lds16(wpack_hi + gb + off, &lds_hi[(c + 1) & 1][off]);
            gload_lds16(wpack_lo + gb + off, &lds_lo[(c + 1) & 1][off]);
        }
        const unsigned short* lbh = lds_hi[c & 1];
        const unsigned short* lbl = lds_lo[c & 1];

        // compute all 4 (mt x tl) acc quads: independent 6-MFMA chains, base fed as C
        f32x4 acc[2][2];
        #pragma unroll
        for (int tl = 0; tl < 2; ++tl) {
            const int fb = tl * 1024 + (quad * 16 + col) * 8;
            half8 bh0 = *(const half8*)(lbh + fb);
            half8 bh1 = *(const half8*)(lbh + fb + 512);
            half8 bl0 = *(const half8*)(lbl + fb);
            half8 bl1 = *(const half8*)(lbl + fb + 512);
            const float base = lds_wn[c * 32 + tl * 16 + col];  // 16384*(128 - 0.5||w||^2)
            f32x4 bv = {base, base, base, base};
            #pragma unroll
            for (int mt = 0; mt < 2; ++mt) {
                f32x4 a;
                a = __builtin_amdgcn_mfma_f32_16x16x32_f16(a_hi[mt][0], bh0, bv, 0, 0, 0);
                a = __builtin_amdgcn_mfma_f32_16x16x32_f16(a_hi[mt][1], bh1, a, 0, 0, 0);
                a = __builtin_amdgcn_mfma_f32_16x16x32_f16(a_lo[mt][0], bh0, a, 0, 0, 0);
                a = __builtin_amdgcn_mfma_f32_16x16x32_f16(a_lo[mt][1], bh1, a, 0, 0, 0);
                a = __builtin_amdgcn_mfma_f32_16x16x32_f16(a_hi[mt][0], bl0, a, 0, 0, 0);
                a = __builtin_amdgcn_mfma_f32_16x16x32_f16(a_hi[mt][1], bl1, a, 0, 0, 0);
                acc[mt][tl] = a;
            }
        }

        // pack (cvt + lshl_or) + top-2-of-2 + merge, per slot
        const unsigned cb0 = 1023u - (unsigned)(c * 32 + col);
        const unsigned cb1 = cb0 - 16u;
        #pragma unroll
        for (int mt = 0; mt < 2; ++mt) {
            #pragma unroll
            for (int r = 0; r < 4; ++r) {
                unsigned p0 = ((unsigned)acc[mt][0][r] << 10) | cb0;
                unsigned p1 = ((unsigned)acc[mt][1][r] << 10) | cb1;
                unsigned m1 = umax(p0, p1), n1 = umin(p0, p1);
                int s = mt * 4 + r;
                unsigned mb = umin(m1, best[s]);
                best[s] = umax(m1, best[s]);
                sec[s]  = umax(sec[s], umax(mb, n1));   // v_max3_u32
            }
        }
        __syncthreads();   // all waves done with buf[c&1]; next chunk's loads drained
    }

    // top-2 merge across the 16 columns
    #pragma unroll
    for (int m = 1; m < 16; m <<= 1) {
        #pragma unroll
        for (int s = 0; s < 8; ++s) {
            unsigned ob = __shfl_xor(best[s], m);
            unsigned os = __shfl_xor(sec[s], m);
            unsigned mn = umin(ob, best[s]);
            best[s] = umax(ob, best[s]);
            sec[s]  = umax(sec[s], umax(os, mn));
        }
    }

    if (col == 0) {
        #pragma unroll
        for (int s = 0; s < 8; ++s) {
            int mt = s >> 2, r = s & 3;
            long long np = n0 + mt * 16 + quad * 4 + r;   // C row = quad*4 + reg
            if (np < N) {
                unsigned code = 1023u - (best[s] & 0x3FFu);
                unsigned gap = (best[s] >> 10) - (sec[s] >> 10);  // fixed-point units (1/16384)
                if (gap < MARGIN_I) {
                    idx_out[np] = code | 0x80000000u;
                    int q = atomicAdd(&l_cnt, 1);        // LDS atomic
                    l_wl[q] = (int)np;
                } else {
                    idx_out[np] = code;
                }
            }
        }
    }
    __syncthreads();
    if (tid == 0 && l_cnt > 0) l_base = atomicAdd(wl_count, l_cnt);  // 1 global RMW/block
    __syncthreads();
    for (int i = tid; i < l_cnt; i += 256) {
        int pos = l_base + i;
        if (pos < WLCAP) wl[pos] = l_wl[i];
    }
}

// ---------------- K3: fp64 exact rescan; one BLOCK per worklist point (4 waves split K) ----------------
__global__ void k_refine(const float* __restrict__ x, const float* __restrict__ w,
                         const double* __restrict__ wn64, unsigned int* __restrict__ idx_io,
                         const int* __restrict__ wl, const int* __restrict__ wl_count,
                         int N, int K)
{
    __shared__ double s_bt[4];
    __shared__ int s_bk[4];
    const int tid = threadIdx.x;
    const int lane = tid & 63, wv = tid >> 6;
    int nw = wl_count[0];
    if (nw > WLCAP) nw = WLCAP;

    for (int i = blockIdx.x; i < nw; i += gridDim.x) {
        long long p = wl[i];
        const float* __restrict__ xp = x + p * D;        // broadcast, L1-hot
        double bt = -1e300;
        int bk = 0;
        #pragma unroll
        for (int kk = 0; kk < KTOT; kk += 256) {
            int k = kk + tid;                            // coalesced over w columns
            double t = 0.0;
            #pragma unroll 8
            for (int d = 0; d < D; ++d)
                t = fma((double)xp[d], (double)w[(size_t)d * K + k], t);
            t -= wn64[k];
            if (t > bt || (t == bt && k < bk)) { bt = t; bk = k; }
        }
        #pragma unroll
        for (int off = 32; off > 0; off >>= 1) {
            double ot = __shfl_down(bt, off);
            int    ok = __shfl_down(bk, off);
            if (ot > bt || (ot == bt && ok < bk)) { bt = ot; bk = ok; }
        }
        if (lane == 0) { s_bt[wv] = bt; s_bk[wv] = bk; }
        __syncthreads();
        if (tid == 0) {
            double b = s_bt[0]; int k0 = s_bk[0];
            #pragma unroll
            for (int j = 1; j < 4; ++j)
                if (s_bt[j] > b || (s_bt[j] == b && s_bk[j] < k0)) { b = s_bt[j]; k0 = s_bk[j]; }
            idx_io[p] = (unsigned)k0;                    // clear flag
        }
        __syncthreads();                                 // protect s_bt/s_bk reuse
    }
}

// ---------------- K4: per-block histogram, plain writes (no global atomics) ----------------
__global__ void k_hist2(const unsigned int* __restrict__ idx, int* __restrict__ hist, int N)
{
    __shared__ int h[KTOT];
    const int tid = threadIdx.x;
    const int b = blockIdx.x;
    for (int i = tid; i < KTOT; i += blockDim.x) h[i] = 0;
    __syncthreads();
    const int chunk = N / NB;
    const int p0 = b * chunk;
    for (int i = tid; i < chunk; i += blockDim.x)
        atomicAdd(&h[idx[p0 + i] & 0x7fffffffu], 1);
    __syncthreads();
    for (int i = tid; i < KTOT; i += blockDim.x)
        hist[(size_t)b * KTOT + i] = h[i];
}

// ---------------- K5: fused per-code block-scan + shfl-based code prefix-scan (1 block, 1024 thr) ----------------
__global__ void k_totscan(int* __restrict__ hist, int* __restrict__ counts,
                          int* __restrict__ offsets)
{
    __shared__ int wsum[16];
    const int k = threadIdx.x;
    int run = 0;
    #pragma unroll 8
    for (int b = 0; b < NB; ++b) {               // coalesced across k
        int t = hist[(size_t)b * KTOT + k];
        hist[(size_t)b * KTOT + k] = run;
        run += t;
    }
    counts[k] = run;
    // inclusive scan within wave (shfl), then scan the 16 wave totals
    int v = run;
    #pragma unroll
    for (int off = 1; off < 64; off <<= 1) {
        int u = __shfl_up(v, off);
        if ((k & 63) >= off) v += u;
    }
    if ((k & 63) == 63) wsum[k >> 6] = v;
    __syncthreads();
    if (k < 16) {
        int s = wsum[k];
        #pragma unroll
        for (int off = 1; off < 16; off <<= 1) {
            int u = __shfl_up(s, off);
            if (k >= off) s += u;
        }
        wsum[k] = s;
    }
    __syncthreads();
    int base = (k >= 64) ? wsum[(k >> 6) - 1] : 0;
    offsets[k] = base + v - run;                 // exclusive prefix over codes
}

// ---------------- K6: place via LDS cursors (zero global atomics) ----------------
__global__ void k_place2(const unsigned int* __restrict__ idx, const int* __restrict__ hist,
                         const int* __restrict__ offsets, unsigned* __restrict__ order, int N)
{
    __shared__ int cur[KTOT];
    const int tid = threadIdx.x;
    const int b = blockIdx.x;
    for (int i = tid; i < KTOT; i += blockDim.x)
        cur[i] = offsets[i] + hist[(size_t)b * KTOT + i];
    __syncthreads();
    const int chunk = N / NB;
    const int p0 = b * chunk;
    for (int i = tid; i < chunk; i += blockDim.x) {
        int p = p0 + i;
        unsigned k = idx[p] & 0x7fffffffu;
        int pos = atomicAdd(&cur[k], 1);         // LDS atomic; worst code ~60 RMWs/block
        order[pos] = (k << 18) | (unsigned)p;
    }
}

// ---------------- K7: balanced run-length segment sum + fused quant gather ----------------
__global__ void k_sum(const float* __restrict__ x, const float* __restrict__ wT,
                      const unsigned* __restrict__ order, float* __restrict__ quant,
                      float* __restrict__ cs, int N)
{
    const int gtid = blockIdx.x * blockDim.x + threadIdx.x;
    const int lane = threadIdx.x & 63;
    const int wave = gtid >> 6;
    const int nwaves = (gridDim.x * blockDim.x) >> 6;
    const int nchunks = (N + 63) >> 6;

    for (int c = wave; c < nchunks; c += nwaves) {
        const int base = c << 6;
        const int cnt = min(64, N - base);
        unsigned e = order[base + min(lane, cnt - 1)];   // coalesced 256B

        int curk = -1;
        float acc = 0.f, wrow = 0.f;
        unsigned e0 = __shfl(e, 0);
        int k0 = (int)(e0 >> 18), p0 = (int)(e0 & PMASK);
        float v = x[(size_t)p0 * D + lane];
        for (int i = 0; i < cnt; ++i) {
            int kn = 0, pn = 0;
            float vn = 0.f;
            if (i + 1 < cnt) {                           // wave-uniform branch
                unsigned en = __shfl(e, i + 1);
                kn = (int)(en >> 18);
                pn = (int)(en & PMASK);
                vn = x[(size_t)pn * D + lane];
            }
            if (k0 != curk) {                            // wave-uniform
                if (curk >= 0) unsafeAtomicAdd(&cs[(size_t)curk * D + lane], acc);
                wrow = wT[(size_t)k0 * D + lane];        // L2-hot, once per run
                acc = v;
                curk = k0;
            } else {
                acc += v;
            }
            quant[(size_t)p0 * D + lane] = wrow;         // store overlaps next x load
            k0 = kn; p0 = pn; v = vn;
        }
        unsafeAtomicAdd(&cs[(size_t)curk * D + lane], acc);
    }
}

// ---------------- K8: EMA combine -> new_w [D][K] ----------------
__global__ void k_combine(const float* __restrict__ c_sum, const float* __restrict__ c_n,
                          const float* __restrict__ cs, const int* __restrict__ counts,
                          float* __restrict__ outw, int K)
{
    int i = blockIdx.x * blockDim.x + threadIdx.x;   // i = d*K + k
    if (i >= D * K) return;
    int k = i % K;
    int d = i / K;
    const float g  = 0.99f;
    const float og = (float)(1.0 - 0.99);
    float ns = c_sum[i] * g + cs[(size_t)k * D + d] * og;
    float nn = c_n[k] * g + (float)counts[k] * og;
    outw[i] = ns / nn;
}

extern "C" void kernel_launch(void* const* d_in, const int* in_sizes, int n_in,
                              void* d_out, int out_size, void* d_ws, size_t ws_size,
                              hipStream_t stream)
{
    const float* x     = (const float*)d_in[0];
    const float* w     = (const float*)d_in[1];
    const float* c_sum = (const float*)d_in[2];
    const float* c_n   = (const float*)d_in[3];
    const int N = in_sizes[0] / D;
    const int K = in_sizes[3];

    float* quant = (float*)d_out;                      // N*D
    float* outw  = (float*)d_out + (size_t)N * D;      // D*K

    // ws layout: [wn64 K (f64)] [cs K*D][wl_count 1]
    //   [hist NB*K][counts K][offsets K][wl WLCAP][order N][idx N][wn K][wT K*D]
    //   [wpack_hi K*D ushort][wpack_lo K*D ushort]
    char* ws = (char*)d_ws;
    double* wn64    = (double*)ws;                     // K (8B aligned at base)
    float* cs       = (float*)(wn64 + K);              // K*D
    int* wl_count   = (int*)(cs + (size_t)K * D);      // 1
    int* hist       = wl_count + 1;                    // NB*K
    int* counts     = hist + (size_t)NB * KTOT;        // K
    int* offsets    = counts + K;                      // K
    int* wl         = offsets + K;                     // WLCAP
    unsigned* order = (unsigned*)(wl + WLCAP);         // N
    unsigned* idx   = order + N;                       // N
    float* wn       = (float*)(idx + N);               // K
    float* wT       = wn + K;                          // K*D
    unsigned short* wpack_hi = (unsigned short*)(wT + (size_t)K * D);  // K*D
    unsigned short* wpack_lo = wpack_hi + (size_t)K * D;               // K*D

    // k_prep also zeroes cs + wl_count (64 extra blocks) -- no memset dispatch
    k_prep<<<(D * K) / 256 + 4 + 64, 256, 0, stream>>>(w, wpack_hi, wpack_lo, wT, wn, wn64,
                                                       cs, wl_count, K);

    k_assign<<<(N + 127) / 128, 256, 0, stream>>>(x, wpack_hi, wpack_lo, wn, idx, wl, wl_count, N, K);
    k_refine<<<1024, 256, 0, stream>>>(x, w, wn64, idx, wl, wl_count, N, K);

    k_hist2<<<NB, 256, 0, stream>>>(idx, hist, N);
    k_totscan<<<1, KTOT, 0, stream>>>(hist, counts, offsets);
    k_place2<<<NB, 256, 0, stream>>>(idx, hist, offsets, order, N);
    k_sum<<<1024, 256, 0, stream>>>(x, wT, order, quant, cs, N);
    k_combine<<<(D * K + 255) / 256, 256, 0, stream>>>(c_sum, c_n, cs, counts, outw, K);
}

// Round 6
// 274.913 us; speedup vs baseline: 1.5380x; 1.5380x over previous
//
#include <hip/hip_runtime.h>
#include <hip/hip_fp16.h>
#include <cmath>

#define D 64
#define KTOT 1024
#define MARGIN_I 32u       // fixed-point margin: 32/16384 = 1.95e-3 (>20 sigma of residual accum err)
#define WLCAP 32768        // refine worklist capacity (expect ~1-2K)
#define PMASK 0x3FFFFu     // low 18 bits: point id (N = 2^18)
#define NB 128             // blocks for hist/place counting sort

typedef __attribute__((ext_vector_type(8))) _Float16 half8;  // 8 fp16 = 4 VGPRs (MFMA A/B frag)
typedef __attribute__((ext_vector_type(4))) float f32x4;     // MFMA C/D frag

static __device__ __forceinline__ unsigned umax(unsigned a, unsigned b) { return a > b ? a : b; }
static __device__ __forceinline__ unsigned umin(unsigned a, unsigned b) { return a < b ? a : b; }

// async global->LDS, 16B per lane. LDS dest must be wave-uniform base + lane*16.
__device__ __forceinline__ void gload_lds16(const unsigned short* g, unsigned short* l)
{
    __builtin_amdgcn_global_load_lds(
        (const __attribute__((address_space(1))) unsigned int*)g,
        (__attribute__((address_space(3))) unsigned int*)l, 16, 0, 0);
}

// ---------------- K0: pack w (x128 prescale, hi+lo fp16) + transpose + wn/wn64 + zero cs ----------------
// blocks [0,nprep): pack; [nprep,nprep+4): wn; [nprep+4,nprep+4+64): zero cs + wl_count
__global__ void k_prep(const float* __restrict__ w, unsigned short* __restrict__ wpack_hi,
                       unsigned short* __restrict__ wpack_lo, float* __restrict__ wT,
                       float* __restrict__ wn, double* __restrict__ wn64,
                       float* __restrict__ cs, int* __restrict__ wl_count, int K)
{
    const int nprep = (D * K) / 256;
    const int bid = blockIdx.x;
    if (bid < nprep) {
        int i = bid * 256 + threadIdx.x;         // i = d*K + k
        int d = i / K, k = i % K;
        float f = w[i];
        _Float16 h = (_Float16)f;                // RNE
        float r = f - (float)h;                  // exact (Sterbenz)
        // prescale by 128 (exact exponent shift): products come out x16384
        _Float16 hs = (_Float16)((float)h * 128.0f);
        _Float16 ls = (_Float16)(r * 128.0f);
        int t = k >> 4, n = k & 15;
        int kc = d >> 5, q = (d >> 3) & 3, j = d & 7;
        size_t fi = ((size_t)((t * 2 + kc) * 64 + q * 16 + n)) * 8 + j;
        wpack_hi[fi] = __half_as_ushort(*(__half*)&hs);
        wpack_lo[fi] = __half_as_ushort(*(__half*)&ls);
        wT[(size_t)k * D + d] = f;
    } else if (bid < nprep + 4) {
        int k = (bid - nprep) * 256 + threadIdx.x;
        if (k >= K) return;
        double s = 0.0;
        for (int d = 0; d < D; ++d) {
            double v = (double)w[(size_t)d * K + k];
            s += v * v;
        }
        wn[k] = 16384.0f * (128.0f - (float)(0.5 * s));  // prescaled biased base
        wn64[k] = 0.5 * s;
    } else {
        int z = bid - nprep - 4;                 // 64 zero-blocks x 1024 floats
        #pragma unroll
        for (int j = 0; j < 4; ++j)
            cs[(size_t)z * 1024 + j * 256 + threadIdx.x] = 0.0f;
        if (z == 0 && threadIdx.x == 0) wl_count[0] = 0;
    }
}

// ---------------- K2: MFMA assign (2-term x, 2-term w; 6 MFMA/tile), batched fixed-point top-2 ----------------
// chunks of 32 codes; dbuf global_load_lds staging; LDS ~21 KB -> 7 blocks/CU via LDS limit.
// launch_bounds min-waves kept at 4: round-5 showed forcing 7 caps VGPR at ~73 -> scratch
// spills (FETCH 306MB, WRITE 576MB). Natural ~56 VGPR already permits 7 blocks; LDS is the limiter.
__global__ __launch_bounds__(256, 4) void k_assign(
    const float* __restrict__ x, const unsigned short* __restrict__ wpack_hi,
    const unsigned short* __restrict__ wpack_lo, const float* __restrict__ wn,
    unsigned int* __restrict__ idx_out, int* __restrict__ wl, int* __restrict__ wl_count,
    int N, int K)
{
    __shared__ __align__(16) unsigned short lds_hi[2][2048];  // 2 x 4 KB (32 codes x 64 d)
    __shared__ __align__(16) unsigned short lds_lo[2][2048];  // 2 x 4 KB
    __shared__ float lds_wn[KTOT];                            // 4 KB, staged once (prescaled base)
    __shared__ int l_wl[128];
    __shared__ int l_cnt, l_base;

    const int tid = threadIdx.x;
    const int wv = tid >> 6, lane = tid & 63;
    const int col = lane & 15, quad = lane >> 4;
    const long long n0 = (long long)blockIdx.x * 128 + wv * 32;
    if (tid == 0) l_cnt = 0;

    // stage all wn (prescaled) once
    #pragma unroll
    for (int i = 0; i < KTOT / 256; ++i)
        lds_wn[tid + 256 * i] = wn[tid + 256 * i];

    // async-stage chunk 0 into buf 0 (hi + lo, 4 KB each = 1 gload each)
    {
        int off = tid * 8;
        gload_lds16(wpack_hi + off, &lds_hi[0][off]);
        gload_lds16(wpack_lo + off, &lds_lo[0][off]);
    }

    // A-frags: x split hi+lo, both prescaled by 128 (exact shifts)
    half8 a_hi[2][2], a_lo[2][2];
    #pragma unroll
    for (int mt = 0; mt < 2; ++mt) {
        long long row = n0 + mt * 16 + col;
        if (row >= N) row = N - 1;
        const float* xr = x + row * D;
        #pragma unroll
        for (int kc = 0; kc < 2; ++kc) {
            const int dbase = kc * 32 + quad * 8;
            float4 f0 = *(const float4*)(xr + dbase);
            float4 f1 = *(const float4*)(xr + dbase + 4);
            float xs[8] = {f0.x, f0.y, f0.z, f0.w, f1.x, f1.y, f1.z, f1.w};
            half8 h, l;
            #pragma unroll
            for (int j = 0; j < 8; ++j) {
                _Float16 hj = (_Float16)xs[j];
                h[j] = (_Float16)((float)hj * 128.0f);
                l[j] = (_Float16)((xs[j] - (float)hj) * 128.0f);
            }
            a_hi[mt][kc] = h;
            a_lo[mt][kc] = l;
        }
    }

    // packed (fixed-point value<<10 | 1023-code): max_u32 argmax, min/max top-2
    unsigned best[8], sec[8];
    #pragma unroll
    for (int s = 0; s < 8; ++s) { best[s] = 0u; sec[s] = 0u; }

    __syncthreads();   // chunk 0 + wn landed (barrier drains vmcnt)

    const int nchunks = K / 32;   // 32
    for (int c = 0; c < nchunks; ++c) {
        if (c + 1 < nchunks) {   // issue next chunk's async loads; drained at end barrier
            const size_t gb = (size_t)(c + 1) * 2048;
            int off = tid * 8;
            gload_lds16(wpack_hi + gb + off, &lds_hi[(c + 1) & 1][off]);
            gload_lds16(wpack_lo + gb + off, &lds_lo[(c + 1) & 1][off]);
        }
        const unsigned short* lbh = lds_hi[c & 1];
        const unsigned short* lbl = lds_lo[c & 1];

        // compute all 4 (mt x tl) acc quads: independent 6-MFMA chains, base fed as C
        f32x4 acc[2][2];
        #pragma unroll
        for (int tl = 0; tl < 2; ++tl) {
            const int fb = tl * 1024 + (quad * 16 + col) * 8;
            half8 bh0 = *(const half8*)(lbh + fb);
            half8 bh1 = *(const half8*)(lbh + fb + 512);
            half8 bl0 = *(const half8*)(lbl + fb);
            half8 bl1 = *(const half8*)(lbl + fb + 512);
            const float base = lds_wn[c * 32 + tl * 16 + col];  // 16384*(128 - 0.5||w||^2)
            f32x4 bv = {base, base, base, base};
            #pragma unroll
            for (int mt = 0; mt < 2; ++mt) {
                f32x4 a;
                a = __builtin_amdgcn_mfma_f32_16x16x32_f16(a_hi[mt][0], bh0, bv, 0, 0, 0);
                a = __builtin_amdgcn_mfma_f32_16x16x32_f16(a_hi[mt][1], bh1, a, 0, 0, 0);
                a = __builtin_amdgcn_mfma_f32_16x16x32_f16(a_lo[mt][0], bh0, a, 0, 0, 0);
                a = __builtin_amdgcn_mfma_f32_16x16x32_f16(a_lo[mt][1], bh1, a, 0, 0, 0);
                a = __builtin_amdgcn_mfma_f32_16x16x32_f16(a_hi[mt][0], bl0, a, 0, 0, 0);
                a = __builtin_amdgcn_mfma_f32_16x16x32_f16(a_hi[mt][1], bl1, a, 0, 0, 0);
                acc[mt][tl] = a;
            }
        }

        // pack (cvt + lshl_or) + top-2-of-2 + merge, per slot
        const unsigned cb0 = 1023u - (unsigned)(c * 32 + col);
        const unsigned cb1 = cb0 - 16u;
        #pragma unroll
        for (int mt = 0; mt < 2; ++mt) {
            #pragma unroll
            for (int r = 0; r < 4; ++r) {
                unsigned p0 = ((unsigned)acc[mt][0][r] << 10) | cb0;
                unsigned p1 = ((unsigned)acc[mt][1][r] << 10) | cb1;
                unsigned m1 = umax(p0, p1), n1 = umin(p0, p1);
                int s = mt * 4 + r;
                unsigned mb = umin(m1, best[s]);
                best[s] = umax(m1, best[s]);
                sec[s]  = umax(sec[s], umax(mb, n1));   // v_max3_u32
            }
        }
        __syncthreads();   // all waves done with buf[c&1]; next chunk's loads drained
    }

    // top-2 merge across the 16 columns
    #pragma unroll
    for (int m = 1; m < 16; m <<= 1) {
        #pragma unroll
        for (int s = 0; s < 8; ++s) {
            unsigned ob = __shfl_xor(best[s], m);
            unsigned os = __shfl_xor(sec[s], m);
            unsigned mn = umin(ob, best[s]);
            best[s] = umax(ob, best[s]);
            sec[s]  = umax(sec[s], umax(os, mn));
        }
    }

    if (col == 0) {
        #pragma unroll
        for (int s = 0; s < 8; ++s) {
            int mt = s >> 2, r = s & 3;
            long long np = n0 + mt * 16 + quad * 4 + r;   // C row = quad*4 + reg
            if (np < N) {
                unsigned code = 1023u - (best[s] & 0x3FFu);
                unsigned gap = (best[s] >> 10) - (sec[s] >> 10);  // fixed-point units (1/16384)
                if (gap < MARGIN_I) {
                    idx_out[np] = code | 0x80000000u;
                    int q = atomicAdd(&l_cnt, 1);        // LDS atomic
                    l_wl[q] = (int)np;
                } else {
                    idx_out[np] = code;
                }
            }
        }
    }
    __syncthreads();
    if (tid == 0 && l_cnt > 0) l_base = atomicAdd(wl_count, l_cnt);  // 1 global RMW/block
    __syncthreads();
    for (int i = tid; i < l_cnt; i += 256) {
        int pos = l_base + i;
        if (pos < WLCAP) wl[pos] = l_wl[i];
    }
}

// ---------------- K3: fp64 exact rescan; one BLOCK per worklist point (4 waves split K) ----------------
__global__ void k_refine(const float* __restrict__ x, const float* __restrict__ w,
                         const double* __restrict__ wn64, unsigned int* __restrict__ idx_io,
                         const int* __restrict__ wl, const int* __restrict__ wl_count,
                         int N, int K)
{
    __shared__ double s_bt[4];
    __shared__ int s_bk[4];
    const int tid = threadIdx.x;
    const int lane = tid & 63, wv = tid >> 6;
    int nw = wl_count[0];
    if (nw > WLCAP) nw = WLCAP;

    for (int i = blockIdx.x; i < nw; i += gridDim.x) {
        long long p = wl[i];
        const float* __restrict__ xp = x + p * D;        // broadcast, L1-hot
        double bt = -1e300;
        int bk = 0;
        #pragma unroll
        for (int kk = 0; kk < KTOT; kk += 256) {
            int k = kk + tid;                            // coalesced over w columns
            double t = 0.0;
            #pragma unroll 8
            for (int d = 0; d < D; ++d)
                t = fma((double)xp[d], (double)w[(size_t)d * K + k], t);
            t -= wn64[k];
            if (t > bt || (t == bt && k < bk)) { bt = t; bk = k; }
        }
        #pragma unroll
        for (int off = 32; off > 0; off >>= 1) {
            double ot = __shfl_down(bt, off);
            int    ok = __shfl_down(bk, off);
            if (ot > bt || (ot == bt && ok < bk)) { bt = ot; bk = ok; }
        }
        if (lane == 0) { s_bt[wv] = bt; s_bk[wv] = bk; }
        __syncthreads();
        if (tid == 0) {
            double b = s_bt[0]; int k0 = s_bk[0];
            #pragma unroll
            for (int j = 1; j < 4; ++j)
                if (s_bt[j] > b || (s_bt[j] == b && s_bk[j] < k0)) { b = s_bt[j]; k0 = s_bk[j]; }
            idx_io[p] = (unsigned)k0;                    // clear flag
        }
        __syncthreads();                                 // protect s_bt/s_bk reuse
    }
}

// ---------------- K4: per-block histogram, plain writes (no global atomics) ----------------
__global__ void k_hist2(const unsigned int* __restrict__ idx, int* __restrict__ hist, int N)
{
    __shared__ int h[KTOT];
    const int tid = threadIdx.x;
    const int b = blockIdx.x;
    for (int i = tid; i < KTOT; i += blockDim.x) h[i] = 0;
    __syncthreads();
    const int chunk = N / NB;
    const int p0 = b * chunk;
    for (int i = tid; i < chunk; i += blockDim.x)
        atomicAdd(&h[idx[p0 + i] & 0x7fffffffu], 1);
    __syncthreads();
    for (int i = tid; i < KTOT; i += blockDim.x)
        hist[(size_t)b * KTOT + i] = h[i];
}

// ---------------- K5: fused per-code block-scan + shfl-based code prefix-scan (1 block, 1024 thr) ----------------
__global__ void k_totscan(int* __restrict__ hist, int* __restrict__ counts,
                          int* __restrict__ offsets)
{
    __shared__ int wsum[16];
    const int k = threadIdx.x;
    int run = 0;
    #pragma unroll 8
    for (int b = 0; b < NB; ++b) {               // coalesced across k
        int t = hist[(size_t)b * KTOT + k];
        hist[(size_t)b * KTOT + k] = run;
        run += t;
    }
    counts[k] = run;
    // inclusive scan within wave (shfl), then scan the 16 wave totals
    int v = run;
    #pragma unroll
    for (int off = 1; off < 64; off <<= 1) {
        int u = __shfl_up(v, off);
        if ((k & 63) >= off) v += u;
    }
    if ((k & 63) == 63) wsum[k >> 6] = v;
    __syncthreads();
    if (k < 16) {
        int s = wsum[k];
        #pragma unroll
        for (int off = 1; off < 16; off <<= 1) {
            int u = __shfl_up(s, off);
            if (k >= off) s += u;
        }
        wsum[k] = s;
    }
    __syncthreads();
    int base = (k >= 64) ? wsum[(k >> 6) - 1] : 0;
    offsets[k] = base + v - run;                 // exclusive prefix over codes
}

// ---------------- K6: place via LDS cursors (zero global atomics) ----------------
__global__ void k_place2(const unsigned int* __restrict__ idx, const int* __restrict__ hist,
                         const int* __restrict__ offsets, unsigned* __restrict__ order, int N)
{
    __shared__ int cur[KTOT];
    const int tid = threadIdx.x;
    const int b = blockIdx.x;
    for (int i = tid; i < KTOT; i += blockDim.x)
        cur[i] = offsets[i] + hist[(size_t)b * KTOT + i];
    __syncthreads();
    const int chunk = N / NB;
    const int p0 = b * chunk;
    for (int i = tid; i < chunk; i += blockDim.x) {
        int p = p0 + i;
        unsigned k = idx[p] & 0x7fffffffu;
        int pos = atomicAdd(&cur[k], 1);         // LDS atomic; worst code ~60 RMWs/block
        order[pos] = (k << 18) | (unsigned)p;
    }
}

// ---------------- K7: balanced run-length segment sum + fused quant gather ----------------
__global__ void k_sum(const float* __restrict__ x, const float* __restrict__ wT,
                      const unsigned* __restrict__ order, float* __restrict__ quant,
                      float* __restrict__ cs, int N)
{
    const int gtid = blockIdx.x * blockDim.x + threadIdx.x;
    const int lane = threadIdx.x & 63;
    const int wave = gtid >> 6;
    const int nwaves = (gridDim.x * blockDim.x) >> 6;
    const int nchunks = (N + 63) >> 6;

    for (int c = wave; c < nchunks; c += nwaves) {
        const int base = c << 6;
        const int cnt = min(64, N - base);
        unsigned e = order[base + min(lane, cnt - 1)];   // coalesced 256B

        int curk = -1;
        float acc = 0.f, wrow = 0.f;
        unsigned e0 = __shfl(e, 0);
        int k0 = (int)(e0 >> 18), p0 = (int)(e0 & PMASK);
        float v = x[(size_t)p0 * D + lane];
        for (int i = 0; i < cnt; ++i) {
            int kn = 0, pn = 0;
            float vn = 0.f;
            if (i + 1 < cnt) {                           // wave-uniform branch
                unsigned en = __shfl(e, i + 1);
                kn = (int)(en >> 18);
                pn = (int)(en & PMASK);
                vn = x[(size_t)pn * D + lane];
            }
            if (k0 != curk) {                            // wave-uniform
                if (curk >= 0) unsafeAtomicAdd(&cs[(size_t)curk * D + lane], acc);
                wrow = wT[(size_t)k0 * D + lane];        // L2-hot, once per run
                acc = v;
                curk = k0;
            } else {
                acc += v;
            }
            quant[(size_t)p0 * D + lane] = wrow;         // store overlaps next x load
            k0 = kn; p0 = pn; v = vn;
        }
        unsafeAtomicAdd(&cs[(size_t)curk * D + lane], acc);
    }
}

// ---------------- K8: EMA combine -> new_w [D][K] ----------------
__global__ void k_combine(const float* __restrict__ c_sum, const float* __restrict__ c_n,
                          const float* __restrict__ cs, const int* __restrict__ counts,
                          float* __restrict__ outw, int K)
{
    int i = blockIdx.x * blockDim.x + threadIdx.x;   // i = d*K + k
    if (i >= D * K) return;
    int k = i % K;
    int d = i / K;
    const float g  = 0.99f;
    const float og = (float)(1.0 - 0.99);
    float ns = c_sum[i] * g + cs[(size_t)k * D + d] * og;
    float nn = c_n[k] * g + (float)counts[k] * og;
    outw[i] = ns / nn;
}

extern "C" void kernel_launch(void* const* d_in, const int* in_sizes, int n_in,
                              void* d_out, int out_size, void* d_ws, size_t ws_size,
                              hipStream_t stream)
{
    const float* x     = (const float*)d_in[0];
    const float* w     = (const float*)d_in[1];
    const float* c_sum = (const float*)d_in[2];
    const float* c_n   = (const float*)d_in[3];
    const int N = in_sizes[0] / D;
    const int K = in_sizes[3];

    float* quant = (float*)d_out;                      // N*D
    float* outw  = (float*)d_out + (size_t)N * D;      // D*K

    // ws layout: [wn64 K (f64)] [cs K*D][wl_count 1]
    //   [hist NB*K][counts K][offsets K][wl WLCAP][order N][idx N][wn K][wT K*D]
    //   [wpack_hi K*D ushort][wpack_lo K*D ushort]
    char* ws = (char*)d_ws;
    double* wn64    = (double*)ws;                     // K (8B aligned at base)
    float* cs       = (float*)(wn64 + K);              // K*D
    int* wl_count   = (int*)(cs + (size_t)K * D);      // 1
    int* hist       = wl_count + 1;                    // NB*K
    int* counts     = hist + (size_t)NB * KTOT;        // K
    int* offsets    = counts + K;                      // K
    int* wl         = offsets + K;                     // WLCAP
    unsigned* order = (unsigned*)(wl + WLCAP);         // N
    unsigned* idx   = order + N;                       // N
    float* wn       = (float*)(idx + N);               // K
    float* wT       = wn + K;                          // K*D
    unsigned short* wpack_hi = (unsigned short*)(wT + (size_t)K * D);  // K*D
    unsigned short* wpack_lo = wpack_hi + (size_t)K * D;               // K*D

    // k_prep also zeroes cs + wl_count (64 extra blocks) -- no memset dispatch
    k_prep<<<(D * K) / 256 + 4 + 64, 256, 0, stream>>>(w, wpack_hi, wpack_lo, wT, wn, wn64,
                                                       cs, wl_count, K);

    k_assign<<<(N + 127) / 128, 256, 0, stream>>>(x, wpack_hi, wpack_lo, wn, idx, wl, wl_count, N, K);
    k_refine<<<1024, 256, 0, stream>>>(x, w, wn64, idx, wl, wl_count, N, K);

    k_hist2<<<NB, 256, 0, stream>>>(idx, hist, N);
    k_totscan<<<1, KTOT, 0, stream>>>(hist, counts, offsets);
    k_place2<<<NB, 256, 0, stream>>>(idx, hist, offsets, order, N);
    k_sum<<<1024, 256, 0, stream>>>(x, wT, order, quant, cs, N);
    k_combine<<<(D * K + 255) / 256, 256, 0, stream>>>(c_sum, c_n, cs, counts, outw, K);
}

// Round 7
// 271.849 us; speedup vs baseline: 1.5553x; 1.0113x over previous
//
#include <hip/hip_runtime.h>
#include <hip/hip_fp16.h>
#include <cmath>

#define D 64
#define KTOT 1024
#define MARGIN_I 32u       // fixed-point margin: 32/16384 = 1.95e-3 (>20 sigma of residual accum err)
#define WLCAP 32768        // refine worklist capacity (expect ~1-2K)
#define PMASK 0x3FFFFu     // low 18 bits: point id (N = 2^18)
#define NB 128             // blocks for hist/place counting sort

typedef __attribute__((ext_vector_type(8))) _Float16 half8;  // 8 fp16 = 4 VGPRs (MFMA A/B frag)
typedef __attribute__((ext_vector_type(4))) float f32x4;     // MFMA C/D frag

static __device__ __forceinline__ unsigned umax(unsigned a, unsigned b) { return a > b ? a : b; }
static __device__ __forceinline__ unsigned umin(unsigned a, unsigned b) { return a < b ? a : b; }

// async global->LDS, 16B per lane. LDS dest must be wave-uniform base + lane*16.
__device__ __forceinline__ void gload_lds16(const unsigned short* g, unsigned short* l)
{
    __builtin_amdgcn_global_load_lds(
        (const __attribute__((address_space(1))) unsigned int*)g,
        (__attribute__((address_space(3))) unsigned int*)l, 16, 0, 0);
}

// ---------------- K0: pack w (x128 prescale, hi+lo fp16) + transpose + wn/wn64 + zero cs ----------------
// blocks [0,nprep): pack; [nprep,nprep+4): wn; [nprep+4,nprep+4+64): zero cs + wl_count
__global__ void k_prep(const float* __restrict__ w, unsigned short* __restrict__ wpack_hi,
                       unsigned short* __restrict__ wpack_lo, float* __restrict__ wT,
                       float* __restrict__ wn, double* __restrict__ wn64,
                       float* __restrict__ cs, int* __restrict__ wl_count, int K)
{
    const int nprep = (D * K) / 256;
    const int bid = blockIdx.x;
    if (bid < nprep) {
        int i = bid * 256 + threadIdx.x;         // i = d*K + k
        int d = i / K, k = i % K;
        float f = w[i];
        _Float16 h = (_Float16)f;                // RNE
        float r = f - (float)h;                  // exact (Sterbenz)
        // prescale by 128 (exact exponent shift): products come out x16384
        _Float16 hs = (_Float16)((float)h * 128.0f);
        _Float16 ls = (_Float16)(r * 128.0f);
        int t = k >> 4, n = k & 15;
        int kc = d >> 5, q = (d >> 3) & 3, j = d & 7;
        size_t fi = ((size_t)((t * 2 + kc) * 64 + q * 16 + n)) * 8 + j;
        wpack_hi[fi] = __half_as_ushort(*(__half*)&hs);
        wpack_lo[fi] = __half_as_ushort(*(__half*)&ls);
        wT[(size_t)k * D + d] = f;
    } else if (bid < nprep + 4) {
        int k = (bid - nprep) * 256 + threadIdx.x;
        if (k >= K) return;
        double s = 0.0;
        for (int d = 0; d < D; ++d) {
            double v = (double)w[(size_t)d * K + k];
            s += v * v;
        }
        wn[k] = 16384.0f * (128.0f - (float)(0.5 * s));  // prescaled biased base
        wn64[k] = 0.5 * s;
    } else {
        int z = bid - nprep - 4;                 // 64 zero-blocks x 1024 floats
        #pragma unroll
        for (int j = 0; j < 4; ++j)
            cs[(size_t)z * 1024 + j * 256 + threadIdx.x] = 0.0f;
        if (z == 0 && threadIdx.x == 0) wl_count[0] = 0;
    }
}

// ---------------- K2: MFMA assign, 512-thr blocks (8 waves, 256 points), 64-code chunks ----------------
// Rationale (r6 post-mortem): occupancy counter pinned at ~36% regardless of LDS size; wall is
// barrier-lockstep. 8-wave blocks halve barriers/point, double compute per stage, halve w L2 traffic.
// LDS ~36 KB; natural VGPR ~56; launch_bounds(512,2) -> VGPR cap 256, no spill (r5 lesson).
__global__ __launch_bounds__(512, 2) void k_assign(
    const float* __restrict__ x, const unsigned short* __restrict__ wpack_hi,
    const unsigned short* __restrict__ wpack_lo, const float* __restrict__ wn,
    unsigned int* __restrict__ idx_out, int* __restrict__ wl, int* __restrict__ wl_count,
    int N, int K)
{
    __shared__ __align__(16) unsigned short lds_hi[2][4096];  // 2 x 8 KB (64 codes x 64 d)
    __shared__ __align__(16) unsigned short lds_lo[2][4096];  // 2 x 8 KB
    __shared__ float lds_wn[KTOT];                            // 4 KB, staged once (prescaled base)
    __shared__ int l_wl[256];
    __shared__ int l_cnt, l_base;

    const int tid = threadIdx.x;
    const int wv = tid >> 6, lane = tid & 63;
    const int col = lane & 15, quad = lane >> 4;
    const long long n0 = (long long)blockIdx.x * 256 + wv * 32;
    if (tid == 0) l_cnt = 0;

    // stage all wn (prescaled) once
    #pragma unroll
    for (int i = 0; i < KTOT / 512; ++i)
        lds_wn[tid + 512 * i] = wn[tid + 512 * i];

    // async-stage chunk 0 into buf 0 (hi + lo, 8 KB each = 1 gload per thread each)
    {
        int off = tid * 8;
        gload_lds16(wpack_hi + off, &lds_hi[0][off]);
        gload_lds16(wpack_lo + off, &lds_lo[0][off]);
    }

    // A-frags: x split hi+lo, both prescaled by 128 (exact shifts)
    half8 a_hi[2][2], a_lo[2][2];
    #pragma unroll
    for (int mt = 0; mt < 2; ++mt) {
        long long row = n0 + mt * 16 + col;
        if (row >= N) row = N - 1;
        const float* xr = x + row * D;
        #pragma unroll
        for (int kc = 0; kc < 2; ++kc) {
            const int dbase = kc * 32 + quad * 8;
            float4 f0 = *(const float4*)(xr + dbase);
            float4 f1 = *(const float4*)(xr + dbase + 4);
            float xs[8] = {f0.x, f0.y, f0.z, f0.w, f1.x, f1.y, f1.z, f1.w};
            half8 h, l;
            #pragma unroll
            for (int j = 0; j < 8; ++j) {
                _Float16 hj = (_Float16)xs[j];
                h[j] = (_Float16)((float)hj * 128.0f);
                l[j] = (_Float16)((xs[j] - (float)hj) * 128.0f);
            }
            a_hi[mt][kc] = h;
            a_lo[mt][kc] = l;
        }
    }

    // packed (fixed-point value<<10 | 1023-code): max_u32 argmax, min/max top-2
    unsigned best[8], sec[8];
    #pragma unroll
    for (int s = 0; s < 8; ++s) { best[s] = 0u; sec[s] = 0u; }

    __syncthreads();   // chunk 0 + wn landed (barrier drains vmcnt)

    const int nchunks = K / 64;   // 16
    for (int c = 0; c < nchunks; ++c) {
        if (c + 1 < nchunks) {   // issue next chunk's async loads; drained at end barrier
            const size_t gb = (size_t)(c + 1) * 4096;
            int off = tid * 8;
            gload_lds16(wpack_hi + gb + off, &lds_hi[(c + 1) & 1][off]);
            gload_lds16(wpack_lo + gb + off, &lds_lo[(c + 1) & 1][off]);
        }
        const unsigned short* lbh = lds_hi[c & 1];
        const unsigned short* lbl = lds_lo[c & 1];

        // compute all 8 (mt x tl) acc quads: independent 6-MFMA chains, base fed as C.
        // setprio(1) across the MFMA cluster (T5): favors MFMA-entering waves over staging waves.
        __builtin_amdgcn_s_setprio(1);
        f32x4 acc[2][4];
        #pragma unroll
        for (int tl = 0; tl < 4; ++tl) {
            const int fb = tl * 1024 + (quad * 16 + col) * 8;
            half8 bh0 = *(const half8*)(lbh + fb);
            half8 bh1 = *(const half8*)(lbh + fb + 512);
            half8 bl0 = *(const half8*)(lbl + fb);
            half8 bl1 = *(const half8*)(lbl + fb + 512);
            const float base = lds_wn[c * 64 + tl * 16 + col];  // 16384*(128 - 0.5||w||^2)
            f32x4 bv = {base, base, base, base};
            #pragma unroll
            for (int mt = 0; mt < 2; ++mt) {
                f32x4 a;
                a = __builtin_amdgcn_mfma_f32_16x16x32_f16(a_hi[mt][0], bh0, bv, 0, 0, 0);
                a = __builtin_amdgcn_mfma_f32_16x16x32_f16(a_hi[mt][1], bh1, a, 0, 0, 0);
                a = __builtin_amdgcn_mfma_f32_16x16x32_f16(a_lo[mt][0], bh0, a, 0, 0, 0);
                a = __builtin_amdgcn_mfma_f32_16x16x32_f16(a_lo[mt][1], bh1, a, 0, 0, 0);
                a = __builtin_amdgcn_mfma_f32_16x16x32_f16(a_hi[mt][0], bl0, a, 0, 0, 0);
                a = __builtin_amdgcn_mfma_f32_16x16x32_f16(a_hi[mt][1], bl1, a, 0, 0, 0);
                acc[mt][tl] = a;
            }
        }
        __builtin_amdgcn_s_setprio(0);

        // pack (cvt + lshl_or) + tree top-2-of-4 + merge, per slot
        unsigned cb[4];
        #pragma unroll
        for (int tl = 0; tl < 4; ++tl)
            cb[tl] = 1023u - (unsigned)(c * 64 + tl * 16 + col);
        #pragma unroll
        for (int mt = 0; mt < 2; ++mt) {
            #pragma unroll
            for (int r = 0; r < 4; ++r) {
                unsigned p0 = ((unsigned)acc[mt][0][r] << 10) | cb[0];
                unsigned p1 = ((unsigned)acc[mt][1][r] << 10) | cb[1];
                unsigned p2 = ((unsigned)acc[mt][2][r] << 10) | cb[2];
                unsigned p3 = ((unsigned)acc[mt][3][r] << 10) | cb[3];
                unsigned m1 = umax(p0, p1), n1 = umin(p0, p1);
                unsigned m2 = umax(p2, p3), n2 = umin(p2, p3);
                unsigned B  = umax(m1, m2), mn = umin(m1, m2);
                unsigned S  = umax(mn, umax(n1, n2));   // true 2nd of 4 (v_max3_u32)
                int s = mt * 4 + r;
                unsigned mb = umin(B, best[s]);
                best[s] = umax(B, best[s]);
                sec[s]  = umax(sec[s], umax(mb, S));    // v_max3_u32
            }
        }
        __syncthreads();   // all waves done with buf[c&1]; next chunk's loads drained
    }

    // top-2 merge across the 16 columns
    #pragma unroll
    for (int m = 1; m < 16; m <<= 1) {
        #pragma unroll
        for (int s = 0; s < 8; ++s) {
            unsigned ob = __shfl_xor(best[s], m);
            unsigned os = __shfl_xor(sec[s], m);
            unsigned mn = umin(ob, best[s]);
            best[s] = umax(ob, best[s]);
            sec[s]  = umax(sec[s], umax(os, mn));
        }
    }

    if (col == 0) {
        #pragma unroll
        for (int s = 0; s < 8; ++s) {
            int mt = s >> 2, r = s & 3;
            long long np = n0 + mt * 16 + quad * 4 + r;   // C row = quad*4 + reg
            if (np < N) {
                unsigned code = 1023u - (best[s] & 0x3FFu);
                unsigned gap = (best[s] >> 10) - (sec[s] >> 10);  // fixed-point units (1/16384)
                if (gap < MARGIN_I) {
                    idx_out[np] = code | 0x80000000u;
                    int q = atomicAdd(&l_cnt, 1);        // LDS atomic
                    l_wl[q] = (int)np;
                } else {
                    idx_out[np] = code;
                }
            }
        }
    }
    __syncthreads();
    if (tid == 0 && l_cnt > 0) l_base = atomicAdd(wl_count, l_cnt);  // 1 global RMW/block
    __syncthreads();
    for (int i = tid; i < l_cnt; i += 512) {
        int pos = l_base + i;
        if (pos < WLCAP) wl[pos] = l_wl[i];
    }
}

// ---------------- K3: fp64 exact rescan; one BLOCK per worklist point (4 waves split K) ----------------
__global__ void k_refine(const float* __restrict__ x, const float* __restrict__ w,
                         const double* __restrict__ wn64, unsigned int* __restrict__ idx_io,
                         const int* __restrict__ wl, const int* __restrict__ wl_count,
                         int N, int K)
{
    __shared__ double s_bt[4];
    __shared__ int s_bk[4];
    const int tid = threadIdx.x;
    const int lane = tid & 63, wv = tid >> 6;
    int nw = wl_count[0];
    if (nw > WLCAP) nw = WLCAP;

    for (int i = blockIdx.x; i < nw; i += gridDim.x) {
        long long p = wl[i];
        const float* __restrict__ xp = x + p * D;        // broadcast, L1-hot
        double bt = -1e300;
        int bk = 0;
        #pragma unroll
        for (int kk = 0; kk < KTOT; kk += 256) {
            int k = kk + tid;                            // coalesced over w columns
            double t = 0.0;
            #pragma unroll 8
            for (int d = 0; d < D; ++d)
                t = fma((double)xp[d], (double)w[(size_t)d * K + k], t);
            t -= wn64[k];
            if (t > bt || (t == bt && k < bk)) { bt = t; bk = k; }
        }
        #pragma unroll
        for (int off = 32; off > 0; off >>= 1) {
            double ot = __shfl_down(bt, off);
            int    ok = __shfl_down(bk, off);
            if (ot > bt || (ot == bt && ok < bk)) { bt = ot; bk = ok; }
        }
        if (lane == 0) { s_bt[wv] = bt; s_bk[wv] = bk; }
        __syncthreads();
        if (tid == 0) {
            double b = s_bt[0]; int k0 = s_bk[0];
            #pragma unroll
            for (int j = 1; j < 4; ++j)
                if (s_bt[j] > b || (s_bt[j] == b && s_bk[j] < k0)) { b = s_bt[j]; k0 = s_bk[j]; }
            idx_io[p] = (unsigned)k0;                    // clear flag
        }
        __syncthreads();                                 // protect s_bt/s_bk reuse
    }
}

// ---------------- K4: per-block histogram, plain writes (no global atomics) ----------------
__global__ void k_hist2(const unsigned int* __restrict__ idx, int* __restrict__ hist, int N)
{
    __shared__ int h[KTOT];
    const int tid = threadIdx.x;
    const int b = blockIdx.x;
    for (int i = tid; i < KTOT; i += blockDim.x) h[i] = 0;
    __syncthreads();
    const int chunk = N / NB;
    const int p0 = b * chunk;
    for (int i = tid; i < chunk; i += blockDim.x)
        atomicAdd(&h[idx[p0 + i] & 0x7fffffffu], 1);
    __syncthreads();
    for (int i = tid; i < KTOT; i += blockDim.x)
        hist[(size_t)b * KTOT + i] = h[i];
}

// ---------------- K5: fused per-code block-scan + shfl-based code prefix-scan (1 block, 1024 thr) ----------------
__global__ void k_totscan(int* __restrict__ hist, int* __restrict__ counts,
                          int* __restrict__ offsets)
{
    __shared__ int wsum[16];
    const int k = threadIdx.x;
    int run = 0;
    #pragma unroll 8
    for (int b = 0; b < NB; ++b) {               // coalesced across k
        int t = hist[(size_t)b * KTOT + k];
        hist[(size_t)b * KTOT + k] = run;
        run += t;
    }
    counts[k] = run;
    // inclusive scan within wave (shfl), then scan the 16 wave totals
    int v = run;
    #pragma unroll
    for (int off = 1; off < 64; off <<= 1) {
        int u = __shfl_up(v, off);
        if ((k & 63) >= off) v += u;
    }
    if ((k & 63) == 63) wsum[k >> 6] = v;
    __syncthreads();
    if (k < 16) {
        int s = wsum[k];
        #pragma unroll
        for (int off = 1; off < 16; off <<= 1) {
            int u = __shfl_up(s, off);
            if (k >= off) s += u;
        }
        wsum[k] = s;
    }
    __syncthreads();
    int base = (k >= 64) ? wsum[(k >> 6) - 1] : 0;
    offsets[k] = base + v - run;                 // exclusive prefix over codes
}

// ---------------- K6: place via LDS cursors (zero global atomics) ----------------
__global__ void k_place2(const unsigned int* __restrict__ idx, const int* __restrict__ hist,
                         const int* __restrict__ offsets, unsigned* __restrict__ order, int N)
{
    __shared__ int cur[KTOT];
    const int tid = threadIdx.x;
    const int b = blockIdx.x;
    for (int i = tid; i < KTOT; i += blockDim.x)
        cur[i] = offsets[i] + hist[(size_t)b * KTOT + i];
    __syncthreads();
    const int chunk = N / NB;
    const int p0 = b * chunk;
    for (int i = tid; i < chunk; i += blockDim.x) {
        int p = p0 + i;
        unsigned k = idx[p] & 0x7fffffffu;
        int pos = atomicAdd(&cur[k], 1);         // LDS atomic; worst code ~60 RMWs/block
        order[pos] = (k << 18) | (unsigned)p;
    }
}

// ---------------- K7: balanced run-length segment sum + fused quant gather ----------------
__global__ void k_sum(const float* __restrict__ x, const float* __restrict__ wT,
                      const unsigned* __restrict__ order, float* __restrict__ quant,
                      float* __restrict__ cs, int N)
{
    const int gtid = blockIdx.x * blockDim.x + threadIdx.x;
    const int lane = threadIdx.x & 63;
    const int wave = gtid >> 6;
    const int nwaves = (gridDim.x * blockDim.x) >> 6;
    const int nchunks = (N + 63) >> 6;

    for (int c = wave; c < nchunks; c += nwaves) {
        const int base = c << 6;
        const int cnt = min(64, N - base);
        unsigned e = order[base + min(lane, cnt - 1)];   // coalesced 256B

        int curk = -1;
        float acc = 0.f, wrow = 0.f;
        unsigned e0 = __shfl(e, 0);
        int k0 = (int)(e0 >> 18), p0 = (int)(e0 & PMASK);
        float v = x[(size_t)p0 * D + lane];
        for (int i = 0; i < cnt; ++i) {
            int kn = 0, pn = 0;
            float vn = 0.f;
            if (i + 1 < cnt) {                           // wave-uniform branch
                unsigned en = __shfl(e, i + 1);
                kn = (int)(en >> 18);
                pn = (int)(en & PMASK);
                vn = x[(size_t)pn * D + lane];
            }
            if (k0 != curk) {                            // wave-uniform
                if (curk >= 0) unsafeAtomicAdd(&cs[(size_t)curk * D + lane], acc);
                wrow = wT[(size_t)k0 * D + lane];        // L2-hot, once per run
                acc = v;
                curk = k0;
            } else {
                acc += v;
            }
            quant[(size_t)p0 * D + lane] = wrow;         // store overlaps next x load
            k0 = kn; p0 = pn; v = vn;
        }
        unsafeAtomicAdd(&cs[(size_t)curk * D + lane], acc);
    }
}

// ---------------- K8: EMA combine -> new_w [D][K] ----------------
__global__ void k_combine(const float* __restrict__ c_sum, const float* __restrict__ c_n,
                          const float* __restrict__ cs, const int* __restrict__ counts,
                          float* __restrict__ outw, int K)
{
    int i = blockIdx.x * blockDim.x + threadIdx.x;   // i = d*K + k
    if (i >= D * K) return;
    int k = i % K;
    int d = i / K;
    const float g  = 0.99f;
    const float og = (float)(1.0 - 0.99);
    float ns = c_sum[i] * g + cs[(size_t)k * D + d] * og;
    float nn = c_n[k] * g + (float)counts[k] * og;
    outw[i] = ns / nn;
}

extern "C" void kernel_launch(void* const* d_in, const int* in_sizes, int n_in,
                              void* d_out, int out_size, void* d_ws, size_t ws_size,
                              hipStream_t stream)
{
    const float* x     = (const float*)d_in[0];
    const float* w     = (const float*)d_in[1];
    const float* c_sum = (const float*)d_in[2];
    const float* c_n   = (const float*)d_in[3];
    const int N = in_sizes[0] / D;
    const int K = in_sizes[3];

    float* quant = (float*)d_out;                      // N*D
    float* outw  = (float*)d_out + (size_t)N * D;      // D*K

    // ws layout: [wn64 K (f64)] [cs K*D][wl_count 1]
    //   [hist NB*K][counts K][offsets K][wl WLCAP][order N][idx N][wn K][wT K*D]
    //   [wpack_hi K*D ushort][wpack_lo K*D ushort]
    char* ws = (char*)d_ws;
    double* wn64    = (double*)ws;                     // K (8B aligned at base)
    float* cs       = (float*)(wn64 + K);              // K*D
    int* wl_count   = (int*)(cs + (size_t)K * D);      // 1
    int* hist       = wl_count + 1;                    // NB*K
    int* counts     = hist + (size_t)NB * KTOT;        // K
    int* offsets    = counts + K;                      // K
    int* wl         = offsets + K;                     // WLCAP
    unsigned* order = (unsigned*)(wl + WLCAP);         // N
    unsigned* idx   = order + N;                       // N
    float* wn       = (float*)(idx + N);               // K
    float* wT       = wn + K;                          // K*D
    unsigned short* wpack_hi = (unsigned short*)(wT + (size_t)K * D);  // K*D
    unsigned short* wpack_lo = wpack_hi + (size_t)K * D;               // K*D

    // k_prep also zeroes cs + wl_count (64 extra blocks) -- no memset dispatch
    k_prep<<<(D * K) / 256 + 4 + 64, 256, 0, stream>>>(w, wpack_hi, wpack_lo, wT, wn, wn64,
                                                       cs, wl_count, K);

    k_assign<<<(N + 255) / 256, 512, 0, stream>>>(x, wpack_hi, wpack_lo, wn, idx, wl, wl_count, N, K);
    k_refine<<<1024, 256, 0, stream>>>(x, w, wn64, idx, wl, wl_count, N, K);

    k_hist2<<<NB, 256, 0, stream>>>(idx, hist, N);
    k_totscan<<<1, KTOT, 0, stream>>>(hist, counts, offsets);
    k_place2<<<NB, 256, 0, stream>>>(idx, hist, offsets, order, N);
    k_sum<<<1024, 256, 0, stream>>>(x, wT, order, quant, cs, N);
    k_combine<<<(D * K + 255) / 256, 256, 0, stream>>>(c_sum, c_n, cs, counts, outw, K);
}

// Round 8
// 271.628 us; speedup vs baseline: 1.5566x; 1.0008x over previous
//
#include <hip/hip_runtime.h>
#include <hip/hip_fp16.h>
#include <cmath>

#define D 64
#define KTOT 1024
#define MARGIN_I 32u       // fixed-point margin: 32/16384 = 1.95e-3 (>20 sigma of residual accum err)
#define WLCAP 32768        // refine worklist capacity (expect ~1-2K)
#define PMASK 0x3FFFFu     // low 18 bits: point id (N = 2^18)
#define NB 128             // blocks for hist/place counting sort

typedef __attribute__((ext_vector_type(8))) _Float16 half8;  // 8 fp16 = 4 VGPRs (MFMA A/B frag)
typedef __attribute__((ext_vector_type(4))) float f32x4;     // MFMA C/D frag

static __device__ __forceinline__ unsigned umax(unsigned a, unsigned b) { return a > b ? a : b; }
static __device__ __forceinline__ unsigned umin(unsigned a, unsigned b) { return a < b ? a : b; }

// async global->LDS, 16B per lane. LDS dest must be wave-uniform base + lane*16.
__device__ __forceinline__ void gload_lds16(const unsigned short* g, unsigned short* l)
{
    __builtin_amdgcn_global_load_lds(
        (const __attribute__((address_space(1))) unsigned int*)g,
        (__attribute__((address_space(3))) unsigned int*)l, 16, 0, 0);
}

// ---------------- K0: pack w (x128 prescale, hi+lo fp16) + transpose + wn/wn64 + zero cs ----------------
// blocks [0,nprep): pack; [nprep,nprep+4): wn; [nprep+4,nprep+4+64): zero cs + wl_count
__global__ void k_prep(const float* __restrict__ w, unsigned short* __restrict__ wpack_hi,
                       unsigned short* __restrict__ wpack_lo, float* __restrict__ wT,
                       float* __restrict__ wn, double* __restrict__ wn64,
                       float* __restrict__ cs, int* __restrict__ wl_count, int K)
{
    const int nprep = (D * K) / 256;
    const int bid = blockIdx.x;
    if (bid < nprep) {
        int i = bid * 256 + threadIdx.x;         // i = d*K + k
        int d = i / K, k = i % K;
        float f = w[i];
        _Float16 h = (_Float16)f;                // RNE
        float r = f - (float)h;                  // exact (Sterbenz)
        // prescale by 128 (exact exponent shift): products come out x16384
        _Float16 hs = (_Float16)((float)h * 128.0f);
        _Float16 ls = (_Float16)(r * 128.0f);
        int t = k >> 4, n = k & 15;
        int kc = d >> 5, q = (d >> 3) & 3, j = d & 7;
        size_t fi = ((size_t)((t * 2 + kc) * 64 + q * 16 + n)) * 8 + j;
        wpack_hi[fi] = __half_as_ushort(*(__half*)&hs);
        wpack_lo[fi] = __half_as_ushort(*(__half*)&ls);
        wT[(size_t)k * D + d] = f;
    } else if (bid < nprep + 4) {
        int k = (bid - nprep) * 256 + threadIdx.x;
        if (k >= K) return;
        double s = 0.0;
        for (int d = 0; d < D; ++d) {
            double v = (double)w[(size_t)d * K + k];
            s += v * v;
        }
        wn[k] = 16384.0f * (128.0f - (float)(0.5 * s));  // prescaled biased base
        wn64[k] = 0.5 * s;
    } else {
        int z = bid - nprep - 4;                 // 64 zero-blocks x 1024 floats
        #pragma unroll
        for (int j = 0; j < 4; ++j)
            cs[(size_t)z * 1024 + j * 256 + threadIdx.x] = 0.0f;
        if (z == 0 && threadIdx.x == 0) wl_count[0] = 0;
    }
}

// ---------------- K2: MFMA assign, 512-thr blocks, counted-vmcnt double-buffer pipeline ----------------
// r7 post-mortem: __syncthreads() in the chunk loop emits vmcnt(0) drain -> every chunk waits the
// NEXT chunk's HBM staging latency (m97 pathology). Fix (T4): raw s_barrier + s_waitcnt vmcnt(2);
// c+2's loads stay in flight across both barriers and hide under chunk c+1's compute.
__global__ __launch_bounds__(512, 2) void k_assign(
    const float* __restrict__ x, const unsigned short* __restrict__ wpack_hi,
    const unsigned short* __restrict__ wpack_lo, const float* __restrict__ wn,
    unsigned int* __restrict__ idx_out, int* __restrict__ wl, int* __restrict__ wl_count,
    int N, int K)
{
    __shared__ __align__(16) unsigned short lds_hi[2][4096];  // 2 x 8 KB (64 codes x 64 d)
    __shared__ __align__(16) unsigned short lds_lo[2][4096];  // 2 x 8 KB
    __shared__ float lds_wn[KTOT];                            // 4 KB, staged once (prescaled base)
    __shared__ int l_wl[256];
    __shared__ int l_cnt, l_base;

    const int tid = threadIdx.x;
    const int wv = tid >> 6, lane = tid & 63;
    const int col = lane & 15, quad = lane >> 4;
    const long long n0 = (long long)blockIdx.x * 256 + wv * 32;
    if (tid == 0) l_cnt = 0;

    // stage all wn (prescaled) once
    #pragma unroll
    for (int i = 0; i < KTOT / 512; ++i)
        lds_wn[tid + 512 * i] = wn[tid + 512 * i];

    // async-stage chunk 0 -> buf0 AND chunk 1 -> buf1 (depth-2 prologue)
    {
        int off = tid * 8;
        gload_lds16(wpack_hi + off, &lds_hi[0][off]);
        gload_lds16(wpack_lo + off, &lds_lo[0][off]);
        gload_lds16(wpack_hi + 4096 + off, &lds_hi[1][off]);
        gload_lds16(wpack_lo + 4096 + off, &lds_lo[1][off]);
    }

    // A-frags: x split hi+lo, both prescaled by 128 (exact shifts)
    half8 a_hi[2][2], a_lo[2][2];
    #pragma unroll
    for (int mt = 0; mt < 2; ++mt) {
        long long row = n0 + mt * 16 + col;
        if (row >= N) row = N - 1;
        const float* xr = x + row * D;
        #pragma unroll
        for (int kc = 0; kc < 2; ++kc) {
            const int dbase = kc * 32 + quad * 8;
            float4 f0 = *(const float4*)(xr + dbase);
            float4 f1 = *(const float4*)(xr + dbase + 4);
            float xs[8] = {f0.x, f0.y, f0.z, f0.w, f1.x, f1.y, f1.z, f1.w};
            half8 h, l;
            #pragma unroll
            for (int j = 0; j < 8; ++j) {
                _Float16 hj = (_Float16)xs[j];
                h[j] = (_Float16)((float)hj * 128.0f);
                l[j] = (_Float16)((xs[j] - (float)hj) * 128.0f);
            }
            a_hi[mt][kc] = h;
            a_lo[mt][kc] = l;
        }
    }

    // packed (fixed-point value<<10 | 1023-code): max_u32 argmax, min/max top-2
    unsigned best[8], sec[8];
    #pragma unroll
    for (int s = 0; s < 8; ++s) { best[s] = 0u; sec[s] = 0u; }

    __syncthreads();   // one-time full drain: wn ds_writes + chunk 0/1 loads all landed

    const int nchunks = K / 64;   // 16
    for (int c = 0; c < nchunks; ++c) {
        const unsigned short* lbh = lds_hi[c & 1];
        const unsigned short* lbl = lds_lo[c & 1];

        // compute all 8 (mt x tl) acc quads: independent 6-MFMA chains, base fed as C.
        __builtin_amdgcn_s_setprio(1);
        f32x4 acc[2][4];
        #pragma unroll
        for (int tl = 0; tl < 4; ++tl) {
            const int fb = tl * 1024 + (quad * 16 + col) * 8;
            half8 bh0 = *(const half8*)(lbh + fb);
            half8 bh1 = *(const half8*)(lbh + fb + 512);
            half8 bl0 = *(const half8*)(lbl + fb);
            half8 bl1 = *(const half8*)(lbl + fb + 512);
            const float base = lds_wn[c * 64 + tl * 16 + col];  // 16384*(128 - 0.5||w||^2)
            f32x4 bv = {base, base, base, base};
            #pragma unroll
            for (int mt = 0; mt < 2; ++mt) {
                f32x4 a;
                a = __builtin_amdgcn_mfma_f32_16x16x32_f16(a_hi[mt][0], bh0, bv, 0, 0, 0);
                a = __builtin_amdgcn_mfma_f32_16x16x32_f16(a_hi[mt][1], bh1, a, 0, 0, 0);
                a = __builtin_amdgcn_mfma_f32_16x16x32_f16(a_lo[mt][0], bh0, a, 0, 0, 0);
                a = __builtin_amdgcn_mfma_f32_16x16x32_f16(a_lo[mt][1], bh1, a, 0, 0, 0);
                a = __builtin_amdgcn_mfma_f32_16x16x32_f16(a_hi[mt][0], bl0, a, 0, 0, 0);
                a = __builtin_amdgcn_mfma_f32_16x16x32_f16(a_hi[mt][1], bl1, a, 0, 0, 0);
                acc[mt][tl] = a;
            }
        }
        __builtin_amdgcn_s_setprio(0);

        // pack (cvt + lshl_or) + tree top-2-of-4 + merge, per slot
        unsigned cb[4];
        #pragma unroll
        for (int tl = 0; tl < 4; ++tl)
            cb[tl] = 1023u - (unsigned)(c * 64 + tl * 16 + col);
        #pragma unroll
        for (int mt = 0; mt < 2; ++mt) {
            #pragma unroll
            for (int r = 0; r < 4; ++r) {
                unsigned p0 = ((unsigned)acc[mt][0][r] << 10) | cb[0];
                unsigned p1 = ((unsigned)acc[mt][1][r] << 10) | cb[1];
                unsigned p2 = ((unsigned)acc[mt][2][r] << 10) | cb[2];
                unsigned p3 = ((unsigned)acc[mt][3][r] << 10) | cb[3];
                unsigned m1 = umax(p0, p1), n1 = umin(p0, p1);
                unsigned m2 = umax(p2, p3), n2 = umin(p2, p3);
                unsigned B  = umax(m1, m2), mn = umin(m1, m2);
                unsigned S  = umax(mn, umax(n1, n2));   // true 2nd of 4 (v_max3_u32)
                int s = mt * 4 + r;
                unsigned mb = umin(B, best[s]);
                best[s] = umax(B, best[s]);
                sec[s]  = umax(sec[s], umax(mb, S));    // v_max3_u32
            }
        }

        // ---- counted-vmcnt pipeline epilogue of the chunk (NO vmcnt(0) drain) ----
        __builtin_amdgcn_s_barrier();            // all waves done reading buf[c&1]
        __builtin_amdgcn_sched_barrier(0);
        if (c + 2 < nchunks) {
            const size_t gb = (size_t)(c + 2) * 4096;
            int off = tid * 8;
            gload_lds16(wpack_hi + gb + off, &lds_hi[c & 1][off]);
            gload_lds16(wpack_lo + gb + off, &lds_lo[c & 1][off]);
            asm volatile("s_waitcnt vmcnt(2)" ::: "memory");  // c+1's pair landed; c+2's in flight
        } else {
            asm volatile("s_waitcnt vmcnt(0)" ::: "memory");  // tail: everything landed
        }
        __builtin_amdgcn_sched_barrier(0);
        __builtin_amdgcn_s_barrier();            // buf[(c+1)&1] ready for ALL waves
        __builtin_amdgcn_sched_barrier(0);
    }

    // top-2 merge across the 16 columns
    #pragma unroll
    for (int m = 1; m < 16; m <<= 1) {
        #pragma unroll
        for (int s = 0; s < 8; ++s) {
            unsigned ob = __shfl_xor(best[s], m);
            unsigned os = __shfl_xor(sec[s], m);
            unsigned mn = umin(ob, best[s]);
            best[s] = umax(ob, best[s]);
            sec[s]  = umax(sec[s], umax(os, mn));
        }
    }

    if (col == 0) {
        #pragma unroll
        for (int s = 0; s < 8; ++s) {
            int mt = s >> 2, r = s & 3;
            long long np = n0 + mt * 16 + quad * 4 + r;   // C row = quad*4 + reg
            if (np < N) {
                unsigned code = 1023u - (best[s] & 0x3FFu);
                unsigned gap = (best[s] >> 10) - (sec[s] >> 10);  // fixed-point units (1/16384)
                if (gap < MARGIN_I) {
                    idx_out[np] = code | 0x80000000u;
                    int q = atomicAdd(&l_cnt, 1);        // LDS atomic
                    l_wl[q] = (int)np;
                } else {
                    idx_out[np] = code;
                }
            }
        }
    }
    __syncthreads();
    if (tid == 0 && l_cnt > 0) l_base = atomicAdd(wl_count, l_cnt);  // 1 global RMW/block
    __syncthreads();
    for (int i = tid; i < l_cnt; i += 512) {
        int pos = l_base + i;
        if (pos < WLCAP) wl[pos] = l_wl[i];
    }
}

// ---------------- K3: fp64 exact rescan; one BLOCK per worklist point (4 waves split K) ----------------
__global__ void k_refine(const float* __restrict__ x, const float* __restrict__ w,
                         const double* __restrict__ wn64, unsigned int* __restrict__ idx_io,
                         const int* __restrict__ wl, const int* __restrict__ wl_count,
                         int N, int K)
{
    __shared__ double s_bt[4];
    __shared__ int s_bk[4];
    const int tid = threadIdx.x;
    const int lane = tid & 63, wv = tid >> 6;
    int nw = wl_count[0];
    if (nw > WLCAP) nw = WLCAP;

    for (int i = blockIdx.x; i < nw; i += gridDim.x) {
        long long p = wl[i];
        const float* __restrict__ xp = x + p * D;        // broadcast, L1-hot
        double bt = -1e300;
        int bk = 0;
        #pragma unroll
        for (int kk = 0; kk < KTOT; kk += 256) {
            int k = kk + tid;                            // coalesced over w columns
            double t = 0.0;
            #pragma unroll 8
            for (int d = 0; d < D; ++d)
                t = fma((double)xp[d], (double)w[(size_t)d * K + k], t);
            t -= wn64[k];
            if (t > bt || (t == bt && k < bk)) { bt = t; bk = k; }
        }
        #pragma unroll
        for (int off = 32; off > 0; off >>= 1) {
            double ot = __shfl_down(bt, off);
            int    ok = __shfl_down(bk, off);
            if (ot > bt || (ot == bt && ok < bk)) { bt = ot; bk = ok; }
        }
        if (lane == 0) { s_bt[wv] = bt; s_bk[wv] = bk; }
        __syncthreads();
        if (tid == 0) {
            double b = s_bt[0]; int k0 = s_bk[0];
            #pragma unroll
            for (int j = 1; j < 4; ++j)
                if (s_bt[j] > b || (s_bt[j] == b && s_bk[j] < k0)) { b = s_bt[j]; k0 = s_bk[j]; }
            idx_io[p] = (unsigned)k0;                    // clear flag
        }
        __syncthreads();                                 // protect s_bt/s_bk reuse
    }
}

// ---------------- K4: per-block histogram, plain writes (no global atomics) ----------------
__global__ void k_hist2(const unsigned int* __restrict__ idx, int* __restrict__ hist, int N)
{
    __shared__ int h[KTOT];
    const int tid = threadIdx.x;
    const int b = blockIdx.x;
    for (int i = tid; i < KTOT; i += blockDim.x) h[i] = 0;
    __syncthreads();
    const int chunk = N / NB;
    const int p0 = b * chunk;
    for (int i = tid; i < chunk; i += blockDim.x)
        atomicAdd(&h[idx[p0 + i] & 0x7fffffffu], 1);
    __syncthreads();
    for (int i = tid; i < KTOT; i += blockDim.x)
        hist[(size_t)b * KTOT + i] = h[i];
}

// ---------------- K5: fused per-code block-scan + shfl-based code prefix-scan (1 block, 1024 thr) ----------------
__global__ void k_totscan(int* __restrict__ hist, int* __restrict__ counts,
                          int* __restrict__ offsets)
{
    __shared__ int wsum[16];
    const int k = threadIdx.x;
    int run = 0;
    #pragma unroll 8
    for (int b = 0; b < NB; ++b) {               // coalesced across k
        int t = hist[(size_t)b * KTOT + k];
        hist[(size_t)b * KTOT + k] = run;
        run += t;
    }
    counts[k] = run;
    // inclusive scan within wave (shfl), then scan the 16 wave totals
    int v = run;
    #pragma unroll
    for (int off = 1; off < 64; off <<= 1) {
        int u = __shfl_up(v, off);
        if ((k & 63) >= off) v += u;
    }
    if ((k & 63) == 63) wsum[k >> 6] = v;
    __syncthreads();
    if (k < 16) {
        int s = wsum[k];
        #pragma unroll
        for (int off = 1; off < 16; off <<= 1) {
            int u = __shfl_up(s, off);
            if (k >= off) s += u;
        }
        wsum[k] = s;
    }
    __syncthreads();
    int base = (k >= 64) ? wsum[(k >> 6) - 1] : 0;
    offsets[k] = base + v - run;                 // exclusive prefix over codes
}

// ---------------- K6: place via LDS cursors (zero global atomics) ----------------
__global__ void k_place2(const unsigned int* __restrict__ idx, const int* __restrict__ hist,
                         const int* __restrict__ offsets, unsigned* __restrict__ order, int N)
{
    __shared__ int cur[KTOT];
    const int tid = threadIdx.x;
    const int b = blockIdx.x;
    for (int i = tid; i < KTOT; i += blockDim.x)
        cur[i] = offsets[i] + hist[(size_t)b * KTOT + i];
    __syncthreads();
    const int chunk = N / NB;
    const int p0 = b * chunk;
    for (int i = tid; i < chunk; i += blockDim.x) {
        int p = p0 + i;
        unsigned k = idx[p] & 0x7fffffffu;
        int pos = atomicAdd(&cur[k], 1);         // LDS atomic; worst code ~60 RMWs/block
        order[pos] = (k << 18) | (unsigned)p;
    }
}

// ---------------- K7: balanced run-length segment sum + fused quant gather ----------------
__global__ void k_sum(const float* __restrict__ x, const float* __restrict__ wT,
                      const unsigned* __restrict__ order, float* __restrict__ quant,
                      float* __restrict__ cs, int N)
{
    const int gtid = blockIdx.x * blockDim.x + threadIdx.x;
    const int lane = threadIdx.x & 63;
    const int wave = gtid >> 6;
    const int nwaves = (gridDim.x * blockDim.x) >> 6;
    const int nchunks = (N + 63) >> 6;

    for (int c = wave; c < nchunks; c += nwaves) {
        const int base = c << 6;
        const int cnt = min(64, N - base);
        unsigned e = order[base + min(lane, cnt - 1)];   // coalesced 256B

        int curk = -1;
        float acc = 0.f, wrow = 0.f;
        unsigned e0 = __shfl(e, 0);
        int k0 = (int)(e0 >> 18), p0 = (int)(e0 & PMASK);
        float v = x[(size_t)p0 * D + lane];
        for (int i = 0; i < cnt; ++i) {
            int kn = 0, pn = 0;
            float vn = 0.f;
            if (i + 1 < cnt) {                           // wave-uniform branch
                unsigned en = __shfl(e, i + 1);
                kn = (int)(en >> 18);
                pn = (int)(en & PMASK);
                vn = x[(size_t)pn * D + lane];
            }
            if (k0 != curk) {                            // wave-uniform
                if (curk >= 0) unsafeAtomicAdd(&cs[(size_t)curk * D + lane], acc);
                wrow = wT[(size_t)k0 * D + lane];        // L2-hot, once per run
                acc = v;
                curk = k0;
            } else {
                acc += v;
            }
            quant[(size_t)p0 * D + lane] = wrow;         // store overlaps next x load
            k0 = kn; p0 = pn; v = vn;
        }
        unsafeAtomicAdd(&cs[(size_t)curk * D + lane], acc);
    }
}

// ---------------- K8: EMA combine -> new_w [D][K] ----------------
__global__ void k_combine(const float* __restrict__ c_sum, const float* __restrict__ c_n,
                          const float* __restrict__ cs, const int* __restrict__ counts,
                          float* __restrict__ outw, int K)
{
    int i = blockIdx.x * blockDim.x + threadIdx.x;   // i = d*K + k
    if (i >= D * K) return;
    int k = i % K;
    int d = i / K;
    const float g  = 0.99f;
    const float og = (float)(1.0 - 0.99);
    float ns = c_sum[i] * g + cs[(size_t)k * D + d] * og;
    float nn = c_n[k] * g + (float)counts[k] * og;
    outw[i] = ns / nn;
}

extern "C" void kernel_launch(void* const* d_in, const int* in_sizes, int n_in,
                              void* d_out, int out_size, void* d_ws, size_t ws_size,
                              hipStream_t stream)
{
    const float* x     = (const float*)d_in[0];
    const float* w     = (const float*)d_in[1];
    const float* c_sum = (const float*)d_in[2];
    const float* c_n   = (const float*)d_in[3];
    const int N = in_sizes[0] / D;
    const int K = in_sizes[3];

    float* quant = (float*)d_out;                      // N*D
    float* outw  = (float*)d_out + (size_t)N * D;      // D*K

    // ws layout: [wn64 K (f64)] [cs K*D][wl_count 1]
    //   [hist NB*K][counts K][offsets K][wl WLCAP][order N][idx N][wn K][wT K*D]
    //   [wpack_hi K*D ushort][wpack_lo K*D ushort]
    char* ws = (char*)d_ws;
    double* wn64    = (double*)ws;                     // K (8B aligned at base)
    float* cs       = (float*)(wn64 + K);              // K*D
    int* wl_count   = (int*)(cs + (size_t)K * D);      // 1
    int* hist       = wl_count + 1;                    // NB*K
    int* counts     = hist + (size_t)NB * KTOT;        // K
    int* offsets    = counts + K;                      // K
    int* wl         = offsets + K;                     // WLCAP
    unsigned* order = (unsigned*)(wl + WLCAP);         // N
    unsigned* idx   = order + N;                       // N
    float* wn       = (float*)(idx + N);               // K
    float* wT       = wn + K;                          // K*D
    unsigned short* wpack_hi = (unsigned short*)(wT + (size_t)K * D);  // K*D
    unsigned short* wpack_lo = wpack_hi + (size_t)K * D;               // K*D

    // k_prep also zeroes cs + wl_count (64 extra blocks) -- no memset dispatch
    k_prep<<<(D * K) / 256 + 4 + 64, 256, 0, stream>>>(w, wpack_hi, wpack_lo, wT, wn, wn64,
                                                       cs, wl_count, K);

    k_assign<<<(N + 255) / 256, 512, 0, stream>>>(x, wpack_hi, wpack_lo, wn, idx, wl, wl_count, N, K);
    k_refine<<<1024, 256, 0, stream>>>(x, w, wn64, idx, wl, wl_count, N, K);

    k_hist2<<<NB, 256, 0, stream>>>(idx, hist, N);
    k_totscan<<<1, KTOT, 0, stream>>>(hist, counts, offsets);
    k_place2<<<NB, 256, 0, stream>>>(idx, hist, offsets, order, N);
    k_sum<<<1024, 256, 0, stream>>>(x, wT, order, quant, cs, N);
    k_combine<<<(D * K + 255) / 256, 256, 0, stream>>>(c_sum, c_n, cs, counts, outw, K);
}